// Round 8
// baseline (361.153 us; speedup 1.0000x reference)
//
#include <hip/hip_runtime.h>
#include <math.h>

#define NBATCH 2
#define CHN    64
#define NYY    80
#define NXX    80
#define NCLS   80
#define NPIX   6400      // 80*80
#define KTOT   512000    // NCLS*NPIX
#define NOUT   85        // 5 + NCLS

typedef float vf4 __attribute__((ext_vector_type(4)));

// output = 2*512000*85 floats = 87,040,000 floats = 21,760,000 float4 quads
#define QTOT   21760000L
#define QF1    7616000L      // conv1_hm: 35%
#define QF2    13056000L     // conv1_wr: 25%
#define QF3    16320000L     // conv2_wr: 15%
                             // hm2flags: 25% (QF3..QTOT)

// ============ K1a: hm 3x3 conv + ReLU, FP64 acc, float LDS ============
// grid (40, 4, 2): x = ytile (2 rows), y = ocg (16 oc), z = batch; 320 thr
__global__ __launch_bounds__(320)
void conv1_hm_kernel(const float* __restrict__ x,
                     const float* __restrict__ w1,
                     const float* __restrict__ b1,
                     double* __restrict__ c1,
                     vf4* __restrict__ outq)
{
    __shared__ float  lx[16][4][84];   // data at cols 1..80, col 0/81 zero; 21.5 KB
    __shared__ double lw[144][16];     // [ic*9+tap][oc_local]; 18.4 KB

    const int yt  = blockIdx.x;
    const int ocg = blockIdx.y;
    const int b   = blockIdx.z;
    const int t   = threadIdx.x;

    const int pxq = t % 80;            // 2-px group
    const int ocq = t / 80;            // 0..3
    const int r   = pxq / 40;          // tile row 0..1
    const int c   = (pxq % 40) * 2;    // col 0..78 (even)
    const int oc0 = ocg * 16 + ocq * 4;
    const int gy0 = yt * 2;

    const float* xin = x + (size_t)b * CHN * NPIX;

    const int bl   = (blockIdx.z * 4 + blockIdx.y) * 40 + blockIdx.x;
    const int gtid = bl * 320 + t;
    const vf4 fz = {0.f, 0.f, 0.f, 0.f};

    double acc[2][4];
    #pragma unroll
    for (int j = 0; j < 2; j++)
        #pragma unroll
        for (int o = 0; o < 4; o++) acc[j][o] = (double)b1[oc0 + o];

    for (int cc = 0; cc < 4; cc++) {
        const int icc = cc * 16;
        __syncthreads();
        // stage x tile (float), data shifted +1 col; halo cols zero
        for (int j = t; j < 1280; j += 320) {
            int ic_l = j / 80; int rem = j % 80;
            int row_l = rem / 20; int c4 = (rem % 20) * 4;
            int gy = gy0 - 1 + row_l;
            float4 v = make_float4(0.f, 0.f, 0.f, 0.f);
            if ((unsigned)gy < 80u)
                v = *(const float4*)(xin + (size_t)(icc + ic_l) * NPIX + gy * NXX + c4);
            lx[ic_l][row_l][c4 + 1] = v.x;
            lx[ic_l][row_l][c4 + 2] = v.y;
            lx[ic_l][row_l][c4 + 3] = v.z;
            lx[ic_l][row_l][c4 + 4] = v.w;
        }
        for (int j = t; j < 64; j += 320) {
            lx[j / 4][j % 4][0]  = 0.f;
            lx[j / 4][j % 4][81] = 0.f;
        }
        for (int j = t; j < 2304; j += 320) {
            int oc_l = j % 16; int k = j / 16;
            int ic_l = k / 9, tap = k % 9;
            lw[k][oc_l] = (double)w1[((size_t)(ocg * 16 + oc_l) * CHN + icc + ic_l) * 9 + tap];
        }
        __syncthreads();
        // zero-fill slice (drains under fp64 compute)
        {
            int i0 = cc * 19, i1 = (cc == 3) ? 75 : cc * 19 + 19;
            for (int i = i0; i < i1; i++) {
                long q = (long)gtid + (long)i * 102400;
                if (q < QF1) __builtin_nontemporal_store(fz, outq + q);
            }
        }
        for (int ic = 0; ic < 16; ic++) {
            // input cols c-1..c+2 live at lx cols c..c+3 (8B-aligned, c even)
            double xw[3][4];
            #pragma unroll
            for (int ky = 0; ky < 3; ky++) {
                const float* row = &lx[ic][r + ky][0];
                float2 a  = *(const float2*)&row[c];
                float2 bb = *(const float2*)&row[c + 2];
                xw[ky][0] = (double)a.x;  xw[ky][1] = (double)a.y;
                xw[ky][2] = (double)bb.x; xw[ky][3] = (double)bb.y;
            }
            #pragma unroll
            for (int ky = 0; ky < 3; ky++)
            #pragma unroll
            for (int kx = 0; kx < 3; kx++) {
                const double* wv = &lw[ic * 9 + ky * 3 + kx][ocq * 4];
                double w0 = wv[0], w1d = wv[1], w2 = wv[2], w3 = wv[3];
                double x0 = xw[ky][kx], x1 = xw[ky][kx + 1];
                acc[0][0] += x0 * w0; acc[0][1] += x0 * w1d;
                acc[0][2] += x0 * w2; acc[0][3] += x0 * w3;
                acc[1][0] += x1 * w0; acc[1][1] += x1 * w1d;
                acc[1][2] += x1 * w2; acc[1][3] += x1 * w3;
            }
        }
    }
    size_t pix = (size_t)(gy0 + r) * NXX + c;
    #pragma unroll
    for (int o = 0; o < 4; o++) {
        double2 v;
        v.x = acc[0][o] > 0.0 ? acc[0][o] : 0.0;
        v.y = acc[1][o] > 0.0 ? acc[1][o] : 0.0;
        *(double2*)(c1 + ((size_t)b * CHN + oc0 + o) * NPIX + pix) = v;
    }
}

// ============ K1b: wh/reg 3x3 conv + ReLU, FP32 ============
// grid (20, 4, 4): x = ytile (4 rows), y = ocg (16 oc), z = img; 320 thr
__global__ __launch_bounds__(320)
void conv1_wr_kernel(const float* __restrict__ x,
                     const float* __restrict__ ww1, const float* __restrict__ wb1,
                     const float* __restrict__ rw1, const float* __restrict__ rb1,
                     float* __restrict__ c1,
                     vf4* __restrict__ outq)
{
    __shared__ float lx[16][6][80];    // 30.7 KB
    __shared__ float lw[144][16];      // 9.2 KB

    const int yt  = blockIdx.x;
    const int ocg = blockIdx.y;
    const int img = blockIdx.z;
    const int t   = threadIdx.x;

    const int head = img >> 1, b = img & 1;
    const float* w1 = (head == 0) ? ww1 : rw1;
    const float* b1 = (head == 0) ? wb1 : rb1;
    const float* xin = x + (size_t)b * CHN * NPIX;

    const int pxq = t % 80;
    const int ocq = t / 80;
    const int r   = pxq / 20;
    const int c   = (pxq % 20) * 4;
    const int oc0 = ocg * 16 + ocq * 4;
    const int gy0 = yt * 4;

    const int bl   = (blockIdx.z * 4 + blockIdx.y) * 20 + blockIdx.x;
    const int gtid = bl * 320 + t;
    const vf4 fz = {0.f, 0.f, 0.f, 0.f};

    float acc[4][4];
    #pragma unroll
    for (int j = 0; j < 4; j++)
        #pragma unroll
        for (int o = 0; o < 4; o++) acc[j][o] = b1[oc0 + o];

    for (int cc = 0; cc < 4; cc++) {
        const int icc = cc * 16;
        __syncthreads();
        for (int j = t; j < 1920; j += 320) {
            int ic_l = j / 120; int rem = j % 120;
            int row_l = rem / 20; int c4 = (rem % 20) * 4;
            int gy = gy0 - 1 + row_l;
            float4 v = make_float4(0.f, 0.f, 0.f, 0.f);
            if ((unsigned)gy < 80u)
                v = *(const float4*)(xin + (size_t)(icc + ic_l) * NPIX + gy * NXX + c4);
            *(float4*)&lx[ic_l][row_l][c4] = v;
        }
        for (int j = t; j < 2304; j += 320) {
            int oc_l = j % 16; int k = j / 16;
            int ic_l = k / 9, tap = k % 9;
            lw[k][oc_l] = w1[((size_t)(ocg * 16 + oc_l) * CHN + icc + ic_l) * 9 + tap];
        }
        __syncthreads();
        {
            int i0 = cc * 14, i1 = (cc == 3) ? 54 : cc * 14 + 14;
            for (int i = i0; i < i1; i++) {
                long q = QF1 + (long)gtid + (long)i * 102400;
                if (q < QF2) __builtin_nontemporal_store(fz, outq + q);
            }
        }
        for (int ic = 0; ic < 16; ic++) {
            float xw[3][6];
            #pragma unroll
            for (int ky = 0; ky < 3; ky++) {
                const float* row = &lx[ic][r + ky][0];
                xw[ky][0] = (c > 0) ? row[c - 1] : 0.f;
                float4 m = *(const float4*)&row[c];
                xw[ky][1] = m.x; xw[ky][2] = m.y;
                xw[ky][3] = m.z; xw[ky][4] = m.w;
                xw[ky][5] = (c < 76) ? row[c + 4] : 0.f;
            }
            #pragma unroll
            for (int ky = 0; ky < 3; ky++)
            #pragma unroll
            for (int kx = 0; kx < 3; kx++) {
                const float* wv = &lw[ic * 9 + ky * 3 + kx][ocq * 4];
                float w0 = wv[0], w1v = wv[1], w2 = wv[2], w3 = wv[3];
                #pragma unroll
                for (int j = 0; j < 4; j++) {
                    float xv = xw[ky][j + kx];
                    acc[j][0] += xv * w0; acc[j][1] += xv * w1v;
                    acc[j][2] += xv * w2; acc[j][3] += xv * w3;
                }
            }
        }
    }
    size_t pix = (size_t)(gy0 + r) * NXX + c;
    #pragma unroll
    for (int o = 0; o < 4; o++) {
        float4 v;
        v.x = fmaxf(acc[0][o], 0.f); v.y = fmaxf(acc[1][o], 0.f);
        v.z = fmaxf(acc[2][o], 0.f); v.w = fmaxf(acc[3][o], 0.f);
        *(float4*)(c1 + ((size_t)img * CHN + oc0 + o) * NPIX + pix) = v;
    }
}

// ============ K2b: wh/reg 1x1 conv + relu, FP32 ============
// grid (25, 4, 2): y = head*2 + ch
__global__ __launch_bounds__(256)
void conv2_wr_kernel(const float* __restrict__ c1,
                     const float* __restrict__ wh_w2, const float* __restrict__ wh_b2,
                     const float* __restrict__ rg_w2, const float* __restrict__ rg_b2,
                     float* __restrict__ wh, float* __restrict__ rg,
                     vf4* __restrict__ outq)
{
    int p  = blockIdx.x * 256 + threadIdx.x;
    int hc = blockIdx.y;
    int b  = blockIdx.z;
    int head = hc >> 1, ch = hc & 1;

    // zero-fill slice
    {
        const int bl   = (blockIdx.z * 4 + blockIdx.y) * 25 + blockIdx.x;
        const int gtid = bl * 256 + threadIdx.x;
        const vf4 fz = {0.f, 0.f, 0.f, 0.f};
        for (int i = 0; i < 64; i++) {
            long q = QF2 + (long)gtid + (long)i * 51200;
            if (q < QF3) __builtin_nontemporal_store(fz, outq + q);
        }
    }

    const float* in = c1 + ((size_t)(head * 2 + b) * CHN) * NPIX;
    const float* w  = (head == 0) ? wh_w2 + (size_t)ch * CHN : rg_w2 + (size_t)ch * CHN;
    float bias      = (head == 0) ? wh_b2[ch] : rg_b2[ch];

    float acc = bias;
    for (int ic = 0; ic < CHN; ic++) acc += in[(size_t)ic * NPIX + p] * w[ic];
    acc = fmaxf(acc, 0.f);
    float* o = (head == 0) ? wh : rg;
    o[((size_t)b * 2 + ch) * NPIX + p] = acc;
}

// ============ K2a+K3a fused: hm 1x1 conv (fp64 logits) + 3x3 maxima ============
// grid (80, 2, 2): x = class, y = half (40 rows), z = batch; 256 thr
__global__ __launch_bounds__(256)
void hm2flags_kernel(const double* __restrict__ c1,
                     const float* __restrict__ w2,
                     const float* __restrict__ b2,
                     double* __restrict__ hm_z,
                     unsigned long long* __restrict__ ballots,
                     unsigned int* __restrict__ counts,
                     vf4* __restrict__ outq)
{
    __shared__ double lz[42 * 80];     // rows y0-1 .. y0+40 (halo); 26.9 KB
    __shared__ double lwv[64];
    __shared__ unsigned int wcnt[52];

    const int c    = blockIdx.x;
    const int half = blockIdx.y;
    const int b    = blockIdx.z;
    const int tid  = threadIdx.x;

    // zero-fill slice
    {
        const int bl   = (blockIdx.z * 2 + blockIdx.y) * 80 + blockIdx.x;
        const int gtid = bl * 256 + tid;
        const vf4 fz = {0.f, 0.f, 0.f, 0.f};
        for (int i = 0; i < 67; i++) {
            long q = QF3 + (long)gtid + (long)i * 81920;
            if (q < QTOT) __builtin_nontemporal_store(fz, outq + q);
        }
    }

    if (tid < 64) lwv[tid] = (double)w2[(size_t)c * CHN + tid];
    __syncthreads();

    const double bias = (double)b2[c];
    const double* in = c1 + (size_t)b * CHN * NPIX;
    const int y0 = half * 40;          // first flagged row; staged rows y0-1 .. y0+40

    for (int j = tid; j < 42 * 80; j += 256) {
        int gy = y0 - 1 + j / 80;
        int px = j % 80;
        double v = -1.0e300;
        if ((unsigned)gy < 80u) {
            int p = gy * 80 + px;
            double a0 = 0.0, a1 = 0.0, a2 = 0.0, a3 = 0.0;
            #pragma unroll
            for (int iq = 0; iq < 16; iq++) {
                a0 += in[(size_t)(iq * 4 + 0) * NPIX + p] * lwv[iq * 4 + 0];
                a1 += in[(size_t)(iq * 4 + 1) * NPIX + p] * lwv[iq * 4 + 1];
                a2 += in[(size_t)(iq * 4 + 2) * NPIX + p] * lwv[iq * 4 + 2];
                a3 += in[(size_t)(iq * 4 + 3) * NPIX + p] * lwv[iq * 4 + 3];
            }
            v = bias + ((a0 + a1) + (a2 + a3));
            hm_z[((size_t)b * NCLS + c) * NPIX + p] = v;  // halo rows: benign dup write
        }
        lz[j] = v;
    }
    __syncthreads();

    const int lane = tid & 63, wave = tid >> 6;
    for (int chunk = 0; chunk < 13; chunk++) {
        int pl = chunk * 256 + tid;            // 0..3199 local within half
        bool flag = false;
        if (pl < 3200) {
            int ly = pl / 80 + 1;              // lz row (1..40)
            int px = pl % 80;
            double s = lz[ly * 80 + px];
            double m = s;
            #pragma unroll
            for (int dy = -1; dy <= 1; dy++) {
                const double* row = &lz[(ly + dy) * 80];
                #pragma unroll
                for (int dx = -1; dx <= 1; dx++) {
                    int xn = px + dx;
                    if ((unsigned)xn < 80u) {
                        double v = row[xn];
                        m = v > m ? v : m;
                    }
                }
            }
            flag = (s == m);
        }
        unsigned long long ball = __ballot(flag);
        int widx = chunk * 4 + wave;           // 0..49 valid
        if (lane == 0 && widx < 50) {
            ballots[((size_t)(b * NCLS + c)) * 100 + half * 50 + widx] = ball;
            wcnt[widx] = __popcll(ball);
        }
    }
    __syncthreads();
    if (tid == 0) {
        unsigned int tot = 0;
        for (int i = 0; i < 50; i++) tot += wcnt[i];
        counts[(b * NCLS + c) * 2 + half] = tot;
    }
}

// ============ K3c: scatter maxima rows (in-block scan, sigmoid here) ============
// grid (80, 2): x = class, y = batch; 256 thr
__global__ __launch_bounds__(256)
void scatter_kernel(const unsigned long long* __restrict__ ballots,
                    const unsigned int* __restrict__ counts,
                    const double* __restrict__ hm_z,
                    const float* __restrict__ wh,
                    const float* __restrict__ rg,
                    const float* __restrict__ offsets,
                    float* __restrict__ out)
{
    __shared__ unsigned long long lball[100];
    __shared__ unsigned int pre[100];
    __shared__ unsigned int csum[160];
    __shared__ unsigned int sbase;

    const int c   = blockIdx.x;
    const int b   = blockIdx.y;
    const int tid = threadIdx.x;

    if (tid < 100) {
        unsigned long long bl = ballots[((size_t)(b * NCLS + c)) * 100 + tid];
        lball[tid] = bl;
        pre[tid] = __popcll(bl);
    }
    for (int i = tid; i < 160; i += 256)       // FIX: load ALL 160 counts
        csum[i] = counts[b * NCLS * 2 + i];
    __syncthreads();
    if (tid == 0) {
        unsigned int bse = 0;
        for (int i = 0; i < 2 * c; i++) bse += csum[i];
        sbase = bse;
        unsigned int run = 0;
        for (int i = 0; i < 100; i++) { unsigned int t = pre[i]; pre[i] = run; run += t; }
    }
    __syncthreads();

    const float offx = offsets[b * 3 + 1];
    const float offy = offsets[b * 3 + 2];
    const int lane = tid & 63, wave = tid >> 6;

    for (int chunk = 0; chunk < 25; chunk++) {
        int p = chunk * 256 + tid;
        unsigned long long ball = lball[chunk * 4 + wave];
        if ((ball >> lane) & 1ull) {
            unsigned int rank = sbase + pre[chunk * 4 + wave]
                              + (unsigned int)__popcll(ball & ((1ull << lane) - 1ull));
            int y = p / 80, xx = p % 80;
            float r0 = rg[((size_t)b * 2 + 0) * NPIX + p];
            float r1 = rg[((size_t)b * 2 + 1) * NPIX + p];
            float w0 = wh[((size_t)b * 2 + 0) * NPIX + p];
            float w1 = wh[((size_t)b * 2 + 1) * NPIX + p];
            double z = hm_z[((size_t)b * NCLS + c) * NPIX + p];
            float s = (float)(1.0 / (1.0 + exp(-z)));

            float cx = ((float)xx + 2.f * offx + r0) * 4.f;
            float cy = ((float)y  + 2.f * offy + r1) * 4.f;

            float* row = out + ((size_t)b * KTOT + rank) * NOUT;
            row[0] = cx;
            row[1] = cy;
            row[2] = w0 * 4.f;
            row[3] = w1 * 4.f;
            row[4] = s;
            row[5 + c] = 1.f;
        }
    }
}

extern "C" void kernel_launch(void* const* d_in, const int* in_sizes, int n_in,
                              void* d_out, int out_size, void* d_ws, size_t ws_size,
                              hipStream_t stream)
{
    const float* x       = (const float*)d_in[0];
    const float* offsets = (const float*)d_in[1];
    const float* hm_w1   = (const float*)d_in[2];
    const float* hm_b1   = (const float*)d_in[3];
    const float* hm_w2   = (const float*)d_in[4];
    const float* hm_b2   = (const float*)d_in[5];
    const float* wh_w1   = (const float*)d_in[6];
    const float* wh_b1   = (const float*)d_in[7];
    const float* wh_w2   = (const float*)d_in[8];
    const float* wh_b2   = (const float*)d_in[9];
    const float* reg_w1  = (const float*)d_in[10];
    const float* reg_b1  = (const float*)d_in[11];
    const float* reg_w2  = (const float*)d_in[12];
    const float* reg_b2  = (const float*)d_in[13];

    float* out = (float*)d_out;
    vf4* outq  = (vf4*)d_out;

    // workspace layout
    char* wp = (char*)d_ws;
    double* c1hm = (double*)wp;                 wp += (size_t)NBATCH * CHN * NPIX * 8;
    double* hm_z = (double*)wp;                 wp += (size_t)NBATCH * NCLS * NPIX * 8;
    float*  c1wr = (float*)wp;                  wp += (size_t)2 * NBATCH * CHN * NPIX * 4;
    float*  wh   = (float*)wp;                  wp += (size_t)NBATCH * 2 * NPIX * 4;
    float*  rg   = (float*)wp;                  wp += (size_t)NBATCH * 2 * NPIX * 4;
    unsigned long long* ballots = (unsigned long long*)wp; wp += (size_t)NBATCH * NCLS * 100 * 8;
    unsigned int* counts = (unsigned int*)wp;

    conv1_hm_kernel<<<dim3(40, 4, 2), 320, 0, stream>>>(x, hm_w1, hm_b1, c1hm, outq);

    conv1_wr_kernel<<<dim3(20, 4, 4), 320, 0, stream>>>(
        x, wh_w1, wh_b1, reg_w1, reg_b1, c1wr, outq);

    conv2_wr_kernel<<<dim3(25, 4, 2), 256, 0, stream>>>(
        c1wr, wh_w2, wh_b2, reg_w2, reg_b2, wh, rg, outq);

    hm2flags_kernel<<<dim3(80, 2, 2), 256, 0, stream>>>(
        c1hm, hm_w2, hm_b2, hm_z, ballots, counts, outq);

    scatter_kernel<<<dim3(80, 2), 256, 0, stream>>>(
        ballots, counts, hm_z, wh, rg, offsets, out);
}

// Round 9
// 154.383 us; speedup vs baseline: 2.3393x; 2.3393x over previous
//
#include <hip/hip_runtime.h>
#include <math.h>

#define NBATCH 2
#define CHN    64
#define NYY    80
#define NXX    80
#define NCLS   80
#define NPIX   6400      // 80*80
#define KTOT   512000    // NCLS*NPIX
#define NOUT   85        // 5 + NCLS
#define NBLK   500       // KTOT / 1024

typedef float vf4 __attribute__((ext_vector_type(4)));

// output = 2*512000*85 floats = 87,040,000 floats = 21,760,000 float4 quads
#define QTOT   21760000L
#define QF1    13056000L     // conv1 (fused): 60%
#define QF2    16320000L     // conv2_hm: 15%
                             // flags: 25% (QF2..QTOT)

// ============ K1: fused 3x3 conv + ReLU (hm fp64-acc | wh/reg fp32) ============
// grid 640 x 320 thr. bl<320: hm (yt=bl%40 2-row tile, ocg=(bl/40)%4, b=bl/160)
//                    bl>=320: wr (yt=blw%20 4-row tile, ocg=(blw/20)%4, img=blw/80)
// Both paths use exactly 39,936 B LDS.
__global__ __launch_bounds__(320)
void conv1_kernel(const float* __restrict__ x,
                  const float* __restrict__ hw1, const float* __restrict__ hb1,
                  const float* __restrict__ ww1, const float* __restrict__ wb1,
                  const float* __restrict__ rw1, const float* __restrict__ rb1,
                  double* __restrict__ c1hm, float* __restrict__ c1wr,
                  vf4* __restrict__ outq)
{
    __shared__ double smem_d[4992];    // 39,936 B shared by both paths
    const int bl = blockIdx.x;
    const int t  = threadIdx.x;

    const int gtid = bl * 320 + t;
    const int nth  = 640 * 320;        // 204800
    const vf4 fz = {0.f, 0.f, 0.f, 0.f};

    if (bl < 320) {
        // ---------------- hm path: fp64 acc, float x-LDS ----------------
        float*  lxf = (float*)smem_d;                    // [16][4][84] = 21,504 B
        double* lwd = (double*)((char*)smem_d + 21504);  // [144][16]   = 18,432 B

        const int yt  = bl % 40;
        const int ocg = (bl / 40) % 4;
        const int b   = bl / 160;

        const int pxq = t % 80;        // 2-px group
        const int ocq = t / 80;        // 0..3
        const int r   = pxq / 40;      // tile row 0..1
        const int c   = (pxq % 40) * 2;
        const int oc0 = ocg * 16 + ocq * 4;
        const int gy0 = yt * 2;

        const float* xin = x + (size_t)b * CHN * NPIX;

        double acc[2][4];
        #pragma unroll
        for (int j = 0; j < 2; j++)
            #pragma unroll
            for (int o = 0; o < 4; o++) acc[j][o] = (double)hb1[oc0 + o];

        for (int cc = 0; cc < 4; cc++) {
            const int icc = cc * 16;
            __syncthreads();
            for (int j = t; j < 1280; j += 320) {
                int ic_l = j / 80; int rem = j % 80;
                int row_l = rem / 20; int c4 = (rem % 20) * 4;
                int gy = gy0 - 1 + row_l;
                float4 v = make_float4(0.f, 0.f, 0.f, 0.f);
                if ((unsigned)gy < 80u)
                    v = *(const float4*)(xin + (size_t)(icc + ic_l) * NPIX + gy * NXX + c4);
                float* dst = &lxf[(ic_l * 4 + row_l) * 84];
                dst[c4 + 1] = v.x; dst[c4 + 2] = v.y;
                dst[c4 + 3] = v.z; dst[c4 + 4] = v.w;
            }
            for (int j = t; j < 64; j += 320) {
                lxf[j * 84 + 0]  = 0.f;   // (j = ic*4+row)
                lxf[j * 84 + 81] = 0.f;
            }
            for (int j = t; j < 2304; j += 320) {
                int oc_l = j % 16; int k = j / 16;
                int ic_l = k / 9, tap = k % 9;
                lwd[k * 16 + oc_l] =
                    (double)hw1[((size_t)(ocg * 16 + oc_l) * CHN + icc + ic_l) * 9 + tap];
            }
            __syncthreads();
            // zero-fill slice (drains under fp64 compute)
            {
                int i0 = cc * 16, i1 = i0 + 16;
                for (int i = i0; i < i1; i++) {
                    long q = (long)gtid + (long)i * nth;
                    if (q < QF1) __builtin_nontemporal_store(fz, outq + q);
                }
            }
            for (int ic = 0; ic < 16; ic++) {
                double xw[3][4];
                #pragma unroll
                for (int ky = 0; ky < 3; ky++) {
                    const float* row = &lxf[(ic * 4 + r + ky) * 84];
                    float2 a  = *(const float2*)&row[c];
                    float2 bb = *(const float2*)&row[c + 2];
                    xw[ky][0] = (double)a.x;  xw[ky][1] = (double)a.y;
                    xw[ky][2] = (double)bb.x; xw[ky][3] = (double)bb.y;
                }
                #pragma unroll
                for (int ky = 0; ky < 3; ky++)
                #pragma unroll
                for (int kx = 0; kx < 3; kx++) {
                    const double* wv = &lwd[(ic * 9 + ky * 3 + kx) * 16 + ocq * 4];
                    double w0 = wv[0], w1d = wv[1], w2 = wv[2], w3 = wv[3];
                    double x0 = xw[ky][kx], x1 = xw[ky][kx + 1];
                    acc[0][0] += x0 * w0; acc[0][1] += x0 * w1d;
                    acc[0][2] += x0 * w2; acc[0][3] += x0 * w3;
                    acc[1][0] += x1 * w0; acc[1][1] += x1 * w1d;
                    acc[1][2] += x1 * w2; acc[1][3] += x1 * w3;
                }
            }
        }
        size_t pix = (size_t)(gy0 + r) * NXX + c;
        #pragma unroll
        for (int o = 0; o < 4; o++) {
            double2 v;
            v.x = acc[0][o] > 0.0 ? acc[0][o] : 0.0;
            v.y = acc[1][o] > 0.0 ? acc[1][o] : 0.0;
            *(double2*)(c1hm + ((size_t)b * CHN + oc0 + o) * NPIX + pix) = v;
        }
    } else {
        // ---------------- wh/reg path: fp32 ----------------
        float* lxw = (float*)smem_d;                     // [16][6][80] = 30,720 B
        float* lwf = (float*)((char*)smem_d + 30720);    // [144][16]   =  9,216 B

        const int blw = bl - 320;
        const int yt  = blw % 20;
        const int ocg = (blw / 20) % 4;
        const int img = blw / 80;      // 0=wh b0, 1=wh b1, 2=reg b0, 3=reg b1

        const int head = img >> 1, b = img & 1;
        const float* w1 = (head == 0) ? ww1 : rw1;
        const float* b1 = (head == 0) ? wb1 : rb1;
        const float* xin = x + (size_t)b * CHN * NPIX;

        const int pxq = t % 80;
        const int ocq = t / 80;
        const int r   = pxq / 20;
        const int c   = (pxq % 20) * 4;
        const int oc0 = ocg * 16 + ocq * 4;
        const int gy0 = yt * 4;

        float acc[4][4];
        #pragma unroll
        for (int j = 0; j < 4; j++)
            #pragma unroll
            for (int o = 0; o < 4; o++) acc[j][o] = b1[oc0 + o];

        for (int cc = 0; cc < 4; cc++) {
            const int icc = cc * 16;
            __syncthreads();
            for (int j = t; j < 1920; j += 320) {
                int ic_l = j / 120; int rem = j % 120;
                int row_l = rem / 20; int c4 = (rem % 20) * 4;
                int gy = gy0 - 1 + row_l;
                float4 v = make_float4(0.f, 0.f, 0.f, 0.f);
                if ((unsigned)gy < 80u)
                    v = *(const float4*)(xin + (size_t)(icc + ic_l) * NPIX + gy * NXX + c4);
                *(float4*)&lxw[(ic_l * 6 + row_l) * 80 + c4] = v;
            }
            for (int j = t; j < 2304; j += 320) {
                int oc_l = j % 16; int k = j / 16;
                int ic_l = k / 9, tap = k % 9;
                lwf[k * 16 + oc_l] =
                    w1[((size_t)(ocg * 16 + oc_l) * CHN + icc + ic_l) * 9 + tap];
            }
            __syncthreads();
            {
                int i0 = cc * 16, i1 = i0 + 16;
                for (int i = i0; i < i1; i++) {
                    long q = (long)gtid + (long)i * nth;
                    if (q < QF1) __builtin_nontemporal_store(fz, outq + q);
                }
            }
            for (int ic = 0; ic < 16; ic++) {
                float xw[3][6];
                #pragma unroll
                for (int ky = 0; ky < 3; ky++) {
                    const float* row = &lxw[(ic * 6 + r + ky) * 80];
                    xw[ky][0] = (c > 0) ? row[c - 1] : 0.f;
                    float4 m = *(const float4*)&row[c];
                    xw[ky][1] = m.x; xw[ky][2] = m.y;
                    xw[ky][3] = m.z; xw[ky][4] = m.w;
                    xw[ky][5] = (c < 76) ? row[c + 4] : 0.f;
                }
                #pragma unroll
                for (int ky = 0; ky < 3; ky++)
                #pragma unroll
                for (int kx = 0; kx < 3; kx++) {
                    const float* wv = &lwf[(ic * 9 + ky * 3 + kx) * 16 + ocq * 4];
                    float w0 = wv[0], w1v = wv[1], w2 = wv[2], w3 = wv[3];
                    #pragma unroll
                    for (int j = 0; j < 4; j++) {
                        float xv = xw[ky][j + kx];
                        acc[j][0] += xv * w0; acc[j][1] += xv * w1v;
                        acc[j][2] += xv * w2; acc[j][3] += xv * w3;
                    }
                }
            }
        }
        size_t pix = (size_t)(gy0 + r) * NXX + c;
        #pragma unroll
        for (int o = 0; o < 4; o++) {
            float4 v;
            v.x = fmaxf(acc[0][o], 0.f); v.y = fmaxf(acc[1][o], 0.f);
            v.z = fmaxf(acc[2][o], 0.f); v.w = fmaxf(acc[3][o], 0.f);
            *(float4*)(c1wr + ((size_t)img * CHN + oc0 + o) * NPIX + pix) = v;
        }
    }
}

// ============ K2a: hm 1x1 conv -> RAW LOGIT, FP64, 4 oc/thread ============
// grid (25, 20, 2), 256 thr
__global__ __launch_bounds__(256)
void conv2_hm_kernel(const double* __restrict__ c1,
                     const float* __restrict__ w2,
                     const float* __restrict__ b2,
                     double* __restrict__ hm_z,
                     vf4* __restrict__ outq)
{
    int p   = blockIdx.x * 256 + threadIdx.x;
    int oc0 = blockIdx.y * 4;
    int b   = blockIdx.z;

    // zero-fill slice (drains under fp64 dot products)
    {
        const int bl   = (blockIdx.z * 20 + blockIdx.y) * 25 + blockIdx.x;
        const int gtid = bl * 256 + threadIdx.x;
        const vf4 fz = {0.f, 0.f, 0.f, 0.f};
        for (int i = 0; i < 13; i++) {
            long q = QF1 + (long)gtid + (long)i * 256000;
            if (q < QF2) __builtin_nontemporal_store(fz, outq + q);
        }
    }

    const double* in = c1 + (size_t)b * CHN * NPIX;
    double acc[4];
    #pragma unroll
    for (int o = 0; o < 4; o++) acc[o] = (double)b2[oc0 + o];

    for (int ic = 0; ic < CHN; ic++) {
        double xv = in[(size_t)ic * NPIX + p];
        #pragma unroll
        for (int o = 0; o < 4; o++)
            acc[o] += xv * (double)w2[(size_t)(oc0 + o) * CHN + ic];
    }
    #pragma unroll
    for (int o = 0; o < 4; o++)
        hm_z[((size_t)b * NCLS + oc0 + o) * NPIX + p] = acc[o];
}

// ============ K2b: wh/reg 1x1 conv + relu, FP32 ============
// grid (25, 4, 2)
__global__ __launch_bounds__(256)
void conv2_wr_kernel(const float* __restrict__ c1,
                     const float* __restrict__ wh_w2, const float* __restrict__ wh_b2,
                     const float* __restrict__ rg_w2, const float* __restrict__ rg_b2,
                     float* __restrict__ wh, float* __restrict__ rg)
{
    int p  = blockIdx.x * 256 + threadIdx.x;
    int hc = blockIdx.y;
    int b  = blockIdx.z;
    int head = hc >> 1, ch = hc & 1;

    const float* in = c1 + ((size_t)(head * 2 + b) * CHN) * NPIX;
    const float* w  = (head == 0) ? wh_w2 + (size_t)ch * CHN : rg_w2 + (size_t)ch * CHN;
    float bias      = (head == 0) ? wh_b2[ch] : rg_b2[ch];

    float acc = bias;
    for (int ic = 0; ic < CHN; ic++) acc += in[(size_t)ic * NPIX + p] * w[ic];
    acc = fmaxf(acc, 0.f);
    float* o = (head == 0) ? wh : rg;
    o[((size_t)b * 2 + ch) * NPIX + p] = acc;
}

// ============ K3a: maxima flags on fp64 LOGITS (sigmoid monotone) ============
// grid (500, 2), 1024 thr
__global__ void flags_kernel(const double* __restrict__ hm_z,
                             unsigned long long* __restrict__ ballots,
                             unsigned int* __restrict__ counts,
                             vf4* __restrict__ outq)
{
    int b = blockIdx.y;
    int k = blockIdx.x * 1024 + threadIdx.x;

    // zero-fill slice
    {
        const int gtid = (b * NBLK + blockIdx.x) * 1024 + threadIdx.x;
        const vf4 fz = {0.f, 0.f, 0.f, 0.f};
        for (int i = 0; i < 6; i++) {
            long q = QF2 + (long)gtid + (long)i * 1024000;
            if (q < QTOT) __builtin_nontemporal_store(fz, outq + q);
        }
    }

    int c = k / NPIX;
    int p = k - c * NPIX;
    int y = p / NXX, xx = p - y * NXX;

    const double* h = hm_z + ((size_t)b * NCLS + c) * NPIX;
    double s = h[p];
    double m = s;
    #pragma unroll
    for (int dy = -1; dy <= 1; dy++) {
        int yy = y + dy;
        if ((unsigned)yy >= (unsigned)NYY) continue;
        const double* hr = h + yy * NXX;
        #pragma unroll
        for (int dx = -1; dx <= 1; dx++) {
            int xn = xx + dx;
            if ((unsigned)xn >= (unsigned)NXX) continue;
            double v = hr[xn];
            m = v > m ? v : m;
        }
    }
    bool flag = (s == m);
    unsigned long long ball = __ballot(flag);
    int lane = threadIdx.x & 63;
    int wave = threadIdx.x >> 6;

    __shared__ unsigned int wcnt[16];
    if (lane == 0) {
        ballots[(size_t)b * 8000 + blockIdx.x * 16 + wave] = ball;
        wcnt[wave] = __popcll(ball);
    }
    __syncthreads();
    if (threadIdx.x == 0) {
        unsigned int tot = 0;
        for (int i = 0; i < 16; i++) tot += wcnt[i];
        counts[b * NBLK + blockIdx.x] = tot;
    }
}

// ============ K3b: exclusive scan of 500 block counts per batch ============
__global__ void scan_kernel(const unsigned int* __restrict__ counts,
                            unsigned int* __restrict__ offs)
{
    int b = blockIdx.x;
    int t = threadIdx.x;
    unsigned int v = (t < NBLK) ? counts[b * NBLK + t] : 0u;
    unsigned int xi = v;
    #pragma unroll
    for (int d = 1; d < 64; d <<= 1) {
        unsigned int n = __shfl_up(xi, d, 64);
        if ((t & 63) >= d) xi += n;
    }
    __shared__ unsigned int wtot[8];
    __shared__ unsigned int wbase[8];
    if ((t & 63) == 63) wtot[t >> 6] = xi;
    __syncthreads();
    if (t == 0) {
        unsigned int a = 0;
        for (int i = 0; i < 8; i++) { wbase[i] = a; a += wtot[i]; }
    }
    __syncthreads();
    unsigned int excl = xi - v + wbase[t >> 6];
    if (t < NBLK) offs[b * NBLK + t] = excl;
}

// ============ K3c: scatter maxima rows (sigmoid only here) ============
// grid (500, 2), 1024 thr
__global__ void scatter_kernel(const unsigned long long* __restrict__ ballots,
                               const unsigned int* __restrict__ offs,
                               const double* __restrict__ hm_z,
                               const float* __restrict__ wh,
                               const float* __restrict__ rg,
                               const float* __restrict__ offsets,
                               float* __restrict__ out)
{
    int b = blockIdx.y;
    int k = blockIdx.x * 1024 + threadIdx.x;
    int lane = threadIdx.x & 63;
    int wave = threadIdx.x >> 6;

    unsigned long long ball = ballots[(size_t)b * 8000 + blockIdx.x * 16 + wave];

    __shared__ unsigned int wc[16];
    __shared__ unsigned int wb[16];
    if (lane == 0) wc[wave] = __popcll(ball);
    __syncthreads();
    if (threadIdx.x == 0) {
        unsigned int a = 0;
        for (int i = 0; i < 16; i++) { wb[i] = a; a += wc[i]; }
    }
    __syncthreads();

    bool flag = (ball >> lane) & 1ull;
    if (!flag) return;

    unsigned int rank = offs[b * NBLK + blockIdx.x] + wb[wave]
                      + (unsigned int)__popcll(ball & ((1ull << lane) - 1ull));

    int c = k / NPIX;
    int p = k - c * NPIX;
    int y = p / NXX, xx = p - y * NXX;

    float offx = offsets[b * 3 + 1];
    float offy = offsets[b * 3 + 2];
    float r0 = rg[((size_t)b * 2 + 0) * NPIX + p];
    float r1 = rg[((size_t)b * 2 + 1) * NPIX + p];
    float w0 = wh[((size_t)b * 2 + 0) * NPIX + p];
    float w1 = wh[((size_t)b * 2 + 1) * NPIX + p];
    double z = hm_z[((size_t)b * NCLS + c) * NPIX + p];
    float s  = (float)(1.0 / (1.0 + exp(-z)));

    float cx = ((float)xx + 2.f * offx + r0) * 4.f;
    float cy = ((float)y  + 2.f * offy + r1) * 4.f;

    float* row = out + ((size_t)b * KTOT + rank) * NOUT;
    row[0] = cx;
    row[1] = cy;
    row[2] = w0 * 4.f;
    row[3] = w1 * 4.f;
    row[4] = s;
    row[5 + c] = 1.f;
}

extern "C" void kernel_launch(void* const* d_in, const int* in_sizes, int n_in,
                              void* d_out, int out_size, void* d_ws, size_t ws_size,
                              hipStream_t stream)
{
    const float* x       = (const float*)d_in[0];
    const float* offsets = (const float*)d_in[1];
    const float* hm_w1   = (const float*)d_in[2];
    const float* hm_b1   = (const float*)d_in[3];
    const float* hm_w2   = (const float*)d_in[4];
    const float* hm_b2   = (const float*)d_in[5];
    const float* wh_w1   = (const float*)d_in[6];
    const float* wh_b1   = (const float*)d_in[7];
    const float* wh_w2   = (const float*)d_in[8];
    const float* wh_b2   = (const float*)d_in[9];
    const float* reg_w1  = (const float*)d_in[10];
    const float* reg_b1  = (const float*)d_in[11];
    const float* reg_w2  = (const float*)d_in[12];
    const float* reg_b2  = (const float*)d_in[13];

    float* out = (float*)d_out;
    vf4* outq  = (vf4*)d_out;

    // workspace layout
    char* wp = (char*)d_ws;
    double* c1hm = (double*)wp;                 wp += (size_t)NBATCH * CHN * NPIX * 8;
    double* hm_z = (double*)wp;                 wp += (size_t)NBATCH * NCLS * NPIX * 8;
    float*  c1wr = (float*)wp;                  wp += (size_t)2 * NBATCH * CHN * NPIX * 4;
    float*  wh   = (float*)wp;                  wp += (size_t)NBATCH * 2 * NPIX * 4;
    float*  rg   = (float*)wp;                  wp += (size_t)NBATCH * 2 * NPIX * 4;
    unsigned long long* ballots = (unsigned long long*)wp; wp += (size_t)NBATCH * 8000 * 8;
    unsigned int* counts = (unsigned int*)wp;   wp += (size_t)NBATCH * NBLK * 4;
    unsigned int* offs   = (unsigned int*)wp;

    conv1_kernel<<<640, 320, 0, stream>>>(
        x, hm_w1, hm_b1, wh_w1, wh_b1, reg_w1, reg_b1, c1hm, c1wr, outq);

    conv2_hm_kernel<<<dim3(25, 20, 2), 256, 0, stream>>>(c1hm, hm_w2, hm_b2, hm_z, outq);

    conv2_wr_kernel<<<dim3(25, 4, 2), 256, 0, stream>>>(
        c1wr, wh_w2, wh_b2, reg_w2, reg_b2, wh, rg);

    flags_kernel<<<dim3(NBLK, 2), 1024, 0, stream>>>(hm_z, ballots, counts, outq);

    scan_kernel<<<2, 512, 0, stream>>>(counts, offs);

    scatter_kernel<<<dim3(NBLK, 2), 1024, 0, stream>>>(
        ballots, offs, hm_z, wh, rg, offsets, out);
}